// Round 16
// baseline (43.139 us; speedup 1.0000x reference)
//
#include <hip/hip_runtime.h>

#define N_NEURONS 100000
#define MAX_DELAY 5
#define NSYN 5
#define T_STEPS 20
#define N_LGN 17400
#define N_BKG 100
#define N_SRC (N_LGN + N_BKG)        // 17500
#define E_REC 2000000
#define E_LGN 600000
#define E_BKG 200000
#define E_EXT (E_LGN + E_BKG)        // 800000
#define DT 1.0f
#define NN_PER_BLK 64
#define NTGT 1563                    // consumer blocks = ceil(N/64)
#define DIRW (NTGT + 1)              // 1564
#define NCHUNK 512                   // producer chunks (2 blocks/CU -> 100% occupancy)
#define CHUNK 1563                   // 512*1563 = 800,256 >= E_EXT
#define RUNW (CHUNK * 4)             // ints per chunk run region (16B records)
#define ASTR 21                      // per-neuron acc stride (20 + 1 pad)
#define SCALE_F 262144.0f            // 2^18 fixed-point; q fits u16 (max ~29K)
#define INV_SCALE (1.0 / 262144.0)

// ---------------- ws layout (4-byte units) ----------------
#define OFF_FLAG   0u                // int[32]: [0]=any-spike flag
#define OFF_BITS   32u               // uint[N_SRC]
#define OFF_DIR    17536u            // int[NCHUNK][DIRW] = 800,768
#define OFF_RUNS   818304u           // int[NCHUNK][CHUNK][4] = 3,201,024
#define OFF_ZBUF   4019328u          // float[5N]  (fallback only)
#define OFF_V      4519328u
#define OFF_R      4619328u
#define OFF_ASC    4719328u          // float[2N]
#define OFF_PR     4919328u          // float[5N]
#define OFF_PC     5419328u          // float[5N]
#define OFF_INPI   5919328u          // int[5N]
// ends 6,419,328 units = 25.7 MB

// Zero flag + build 20-bit spike masks.
__global__ void prep(const float* __restrict__ lgn, const float* __restrict__ bkg,
                     unsigned* __restrict__ bits, int* __restrict__ zp) {
    int tid = blockIdx.x * blockDim.x + threadIdx.x;
    if (tid < 32) zp[tid] = 0;
    int i = tid - 32;
    if (i < 0 || i >= N_SRC) return;
    unsigned b = 0;
    if (i < N_LGN) {
#pragma unroll
        for (int t = 0; t < T_STEPS; ++t)
            if (lgn[t * N_LGN + i] != 0.0f) b |= (1u << t);
    } else {
        int j = i - N_LGN;
#pragma unroll
        for (int t = 0; t < T_STEPS; ++t)
            if (bkg[t * N_BKG + j] != 0.0f) b |= (1u << t);
    }
    bits[i] = b;
}

// Counting-sort pack: full occupancy (512 blocks = 2/CU, 32 waves/CU),
// single-pass register loads, LDS record staging, coalesced streaming out.
// Zero global atomics; slot order varies across replays (LDS cursor) but
// consumer integer accumulation is order-invariant -> deterministic output.
__global__ void __launch_bounds__(1024) sort_pack(
    const int* __restrict__ lgn_idx, const float* __restrict__ lgn_w,
    const float* __restrict__ lgn_fac,
    const int* __restrict__ bkg_idx, const float* __restrict__ bkg_w,
    const float* __restrict__ bkg_fac,
    const unsigned* __restrict__ bits,
    int* __restrict__ dir, int* __restrict__ runs)
{
    __shared__ int hist[NTGT];
    __shared__ int cur[NTGT];
    __shared__ int wsum[16];
    __shared__ int totS;
    __shared__ int4 stage[CHUNK];          // 25 KB staging
    int tid = threadIdx.x, c = blockIdx.x;
    int e0 = c * CHUNK;
    int e1 = e0 + CHUNK; if (e1 > E_EXT) e1 = E_EXT;

    for (int i = tid; i < NTGT; i += 1024) hist[i] = 0;

    // Load + quantize both edges into packed registers up front (latency
    // hides under LDS zero + scan).
    int w00 = 0, w10 = 0, w20 = 0, w30 = 0, h0 = 0; bool a0v = false;
    int w01 = 0, w11 = 0, w21 = 0, w31 = 0, h1 = 0; bool a1v = false;
    {
        int e = e0 + tid;
        if (e < e1) {
            int post, srow;
            if (e < E_LGN) { int2 p = ((const int2*)lgn_idx)[e]; post = p.x; srow = p.y; }
            else           { int2 p = ((const int2*)bkg_idx)[e - E_LGN]; post = p.x; srow = N_LGN + p.y; }
            unsigned m = bits[srow];
            if (m) {
                float w; const float* f;
                if (e < E_LGN) { w = lgn_w[e]; f = lgn_fac + 5 * (size_t)e; }
                else { int b = e - E_LGN; w = bkg_w[b]; f = bkg_fac + 5 * (size_t)b; }
                float wsc = w * SCALE_F;
                int q0 = __float2int_rn(wsc * f[0]);
                int q1 = __float2int_rn(wsc * f[1]);
                int q2 = __float2int_rn(wsc * f[2]);
                int q3 = __float2int_rn(wsc * f[3]);
                int q4 = __float2int_rn(wsc * f[4]);
                w00 = (int)(m | ((unsigned)(post & 63) << 20));
                w10 = q0 | (q1 << 16);
                w20 = q2 | (q3 << 16);
                w30 = q4;
                h0 = post >> 6; a0v = true;
            }
        }
    }
    {
        int e = e0 + tid + 1024;
        if (e < e1) {
            int post, srow;
            if (e < E_LGN) { int2 p = ((const int2*)lgn_idx)[e]; post = p.x; srow = p.y; }
            else           { int2 p = ((const int2*)bkg_idx)[e - E_LGN]; post = p.x; srow = N_LGN + p.y; }
            unsigned m = bits[srow];
            if (m) {
                float w; const float* f;
                if (e < E_LGN) { w = lgn_w[e]; f = lgn_fac + 5 * (size_t)e; }
                else { int b = e - E_LGN; w = bkg_w[b]; f = bkg_fac + 5 * (size_t)b; }
                float wsc = w * SCALE_F;
                int q0 = __float2int_rn(wsc * f[0]);
                int q1 = __float2int_rn(wsc * f[1]);
                int q2 = __float2int_rn(wsc * f[2]);
                int q3 = __float2int_rn(wsc * f[3]);
                int q4 = __float2int_rn(wsc * f[4]);
                w01 = (int)(m | ((unsigned)(post & 63) << 20));
                w11 = q0 | (q1 << 16);
                w21 = q2 | (q3 << 16);
                w31 = q4;
                h1 = post >> 6; a1v = true;
            }
        }
    }
    __syncthreads();

    if (a0v) atomicAdd(&hist[h0], 1);
    if (a1v) atomicAdd(&hist[h1], 1);
    __syncthreads();

    // Exclusive scan over 1563 entries: 2/thread + wave-shuffle scan.
    int base = tid * 2;
    int v0 = (base < NTGT) ? hist[base] : 0;
    int v1 = (base + 1 < NTGT) ? hist[base + 1] : 0;
    int s = v0 + v1;
    int lane = tid & 63, wid = tid >> 6;
    int inc = s;
#pragma unroll
    for (int off = 1; off < 64; off <<= 1) {
        int v = __shfl_up(inc, off);
        if (lane >= off) inc += v;
    }
    if (lane == 63) wsum[wid] = inc;
    __syncthreads();
    if (tid < 16) {
        int x = wsum[tid];
        int i2 = x;
#pragma unroll
        for (int off = 1; off < 16; off <<= 1) {
            int u = __shfl_up(i2, off);
            if (tid >= off) i2 += u;
        }
        wsum[tid] = i2 - x;   // exclusive wave offset
    }
    __syncthreads();
    int excl = wsum[wid] + (inc - s);
    if (base < NTGT) {
        cur[base] = excl;
        dir[(size_t)c * DIRW + base] = excl;
    }
    if (base + 1 <= NTGT) {
        if (base + 1 < NTGT) cur[base + 1] = excl + v0;
        else totS = excl + v0;                          // total firing count
        dir[(size_t)c * DIRW + base + 1] = excl + v0;   // base+1==NTGT -> total
    }
    __syncthreads();

    // Stage records at LDS-cursor slots.
    if (a0v) {
        int slot = atomicAdd(&cur[h0], 1);              // LDS atomic
        stage[slot] = make_int4(w00, w10, w20, w30);
    }
    if (a1v) {
        int slot = atomicAdd(&cur[h1], 1);
        stage[slot] = make_int4(w01, w11, w21, w31);
    }
    __syncthreads();

    // Stream staging to global, fully coalesced (full 64B lines).
    int tot = totS;
    int* run = runs + (size_t)c * RUNW;
    for (int k2 = tid; k2 < tot; k2 += 1024)
        *(int4*)(run + (size_t)k2 * 4) = stage[k2];
}

// Consumer (XCD-swizzled blockIdx): thread t streams chunks {t, t+256} for
// this block (ONE int4 load per record), 3 LDS atomics per spike-bit
// (u64-packed pairs; non-negative fields, no carry -> exact, order-invariant);
// then 64 threads run the 20-step GLIF scan.
__global__ void __launch_bounds__(256) fused_scan(
    const int* __restrict__ dir, const int* __restrict__ runs,
    const float* __restrict__ decay, const float* __restrict__ cf,
    const float* __restrict__ vres, const float* __restrict__ tref,
    const float* __restrict__ kk, const float* __restrict__ aamps,
    const float* __restrict__ vth, const float* __restrict__ norm,
    const float* __restrict__ gg, const float* __restrict__ sdec,
    const float* __restrict__ psci,
    float* __restrict__ out, int* __restrict__ flag)
{
    __shared__ unsigned long long a01[NN_PER_BLK * ASTR];   // q0 | q1<<32
    __shared__ unsigned long long a23[NN_PER_BLK * ASTR];   // q2 | q3<<32
    __shared__ unsigned a4[NN_PER_BLK * ASTR];
    int tid = threadIdx.x;
    // Bijective XCD swizzle (NTGT = 1563 = 8*195+3).
    int bid = blockIdx.x;
    int xcd = bid & 7, idx = bid >> 3;
    int b = (xcd < 3) ? (xcd * 196 + idx) : (588 + (xcd - 3) * 195 + idx);
    int n0 = b * NN_PER_BLK;

    for (int i = tid; i < NN_PER_BLK * ASTR; i += 256) { a01[i] = 0ull; a23[i] = 0ull; a4[i] = 0u; }
    __syncthreads();

    for (int cc = tid; cc < NCHUNK; cc += 256) {
        const int* dp = dir + (size_t)cc * DIRW + b;
        int d0 = dp[0], d1 = dp[1];
        const int* run = runs + (size_t)cc * RUNW;
        for (int k = d0; k < d1; ++k) {
            int4 r = *(const int4*)(run + (size_t)k * 4);
            unsigned w0 = (unsigned)r.x;
            unsigned m = w0 & 0xFFFFFu;
            int pl = (int)(w0 >> 20);
            unsigned long long q01 = (unsigned long long)((unsigned)r.y & 0xFFFFu)
                                   | ((unsigned long long)((unsigned)r.y >> 16) << 32);
            unsigned long long q23 = (unsigned long long)((unsigned)r.z & 0xFFFFu)
                                   | ((unsigned long long)((unsigned)r.z >> 16) << 32);
            unsigned q4v = (unsigned)r.w;
            int basei = pl * ASTR;
            while (m) {
                int t = __ffs(m) - 1;
                m &= m - 1;
                atomicAdd(&a01[basei + t], q01);
                atomicAdd(&a23[basei + t], q23);
                atomicAdd(&a4[basei + t], q4v);
            }
        }
    }
    __syncthreads();

    if (tid >= NN_PER_BLK) return;
    int n = n0 + tid;
    if (n >= N_NEURONS) return;

    float dec = decay[n], cfa = cf[n], vr = vres[n], tr = tref[n];
    float ek0 = expf(-DT * kk[2 * n]), ek1 = expf(-DT * kk[2 * n + 1]);
    float aa0 = aamps[2 * n], aa1 = aamps[2 * n + 1];
    float vt = vth[n], nm = norm[n], g = gg[n];
    float sd0 = sdec[0], sd1 = sdec[1], sd2 = sdec[2], sd3 = sdec[3], sd4 = sdec[4];
    float pi0 = psci[0], pi1 = psci[1], pi2 = psci[2], pi3 = psci[3], pi4 = psci[4];

    float pr0 = 0.f, pr1 = 0.f, pr2 = 0.f, pr3 = 0.f, pr4 = 0.f;
    float pc0 = 0.f, pc1 = 0.f, pc2 = 0.f, pc3 = 0.f, pc4 = 0.f;
    float v = 0.f, r = 0.f, a0 = 0.f, a1 = 0.f, pz = 0.f;
    bool anyf = false;
    int basei = tid * ASTR;

#pragma unroll
    for (int t = 0; t < T_STEPS; ++t) {
        float ic = pc0 + pc1 + pc2 + pc3 + pc4;      // input_current uses OLD psc
        float c1 = ic + a0 + a1 + g;
        float dv = dec * v + cfa * c1;
        float nv = (pz > 0.5f) ? vr : dv;
        float nr = r + pz * tr - DT;
        nr = fminf(fmaxf(nr, 0.0f), tr);
        a0 = ek0 * a0 + pz * aa0;
        a1 = ek1 * a1 + pz * aa1;

        unsigned long long v01 = a01[basei + t];
        unsigned long long v23 = a23[basei + t];
        float i0 = (float)((double)(unsigned)(v01 & 0xFFFFFFFFull) * INV_SCALE);
        float i1 = (float)((double)(unsigned)(v01 >> 32) * INV_SCALE);
        float i2 = (float)((double)(unsigned)(v23 & 0xFFFFFFFFull) * INV_SCALE);
        float i3 = (float)((double)(unsigned)(v23 >> 32) * INV_SCALE);
        float i4 = (float)((double)a4[basei + t] * INV_SCALE);

        float np0 = pc0 * sd0 + DT * sd0 * pr0;      // new psc from OLD psc_rise
        float np1 = pc1 * sd1 + DT * sd1 * pr1;
        float np2 = pc2 * sd2 + DT * sd2 * pr2;
        float np3 = pc3 * sd3 + DT * sd3 * pr3;
        float np4 = pc4 * sd4 + DT * sd4 * pr4;
        pr0 = pr0 * sd0 + i0 * pi0;  pc0 = np0;
        pr1 = pr1 * sd1 + i1 * pi1;  pc1 = np1;
        pr2 = pr2 * sd2 + i2 * pi2;  pc2 = np2;
        pr3 = pr3 * sd3 + i3 * pi3;  pc3 = np3;
        pr4 = pr4 * sd4 + i4 * pi4;  pc4 = np4;

        v = nv; r = nr;
        float vsc = (nv - vt) / nm;
        float z = (vsc > 0.0f) ? 1.0f : 0.0f;
        float nz = (nr > 0.0f) ? 0.0f : z;
        out[(size_t)t * N_NEURONS + n] = nz;
        pz = nz;
        anyf = anyf || (nz != 0.0f);
    }
    if (anyf) atomicAdd(flag, 1);
}

// Exact coupled redo inside ONE workgroup; early-exits if no spike detected.
__global__ void __launch_bounds__(1024) fallback_redo(
    const int* __restrict__ dir, const int* __restrict__ runs,
    const int* __restrict__ rec_idx, const float* __restrict__ rec_w,
    const float* __restrict__ rec_fac,
    const float* __restrict__ decay, const float* __restrict__ cf,
    const float* __restrict__ vres, const float* __restrict__ tref,
    const float* __restrict__ kk, const float* __restrict__ aamps,
    const float* __restrict__ vth, const float* __restrict__ norm,
    const float* __restrict__ gg, const float* __restrict__ sdec,
    const float* __restrict__ psci,
    float* __restrict__ zbuf, float* __restrict__ vv, float* __restrict__ rr,
    float* __restrict__ asc, float* __restrict__ pra, float* __restrict__ pca,
    int* __restrict__ inpi, float* __restrict__ out, const int* __restrict__ flag)
{
    if (flag[0] == 0) return;
    int tid = threadIdx.x;
    for (int i = tid; i < N_NEURONS; i += 1024) { vv[i] = 0.f; rr[i] = 0.f; }
    for (int i = tid; i < 2 * N_NEURONS; i += 1024) asc[i] = 0.f;
    for (int i = tid; i < NSYN * N_NEURONS; i += 1024) { pra[i] = 0.f; pca[i] = 0.f; }
    for (int i = tid; i < MAX_DELAY * N_NEURONS; i += 1024) zbuf[i] = 0.f;
    __syncthreads();

    for (int t = 0; t < T_STEPS; ++t) {
        for (int i = tid; i < NSYN * N_NEURONS; i += 1024) inpi[i] = 0;
        __syncthreads();
        for (int cc = tid; cc < NCHUNK; cc += 1024) {
            const int* dp  = dir + (size_t)cc * DIRW;
            const int* run = runs + (size_t)cc * RUNW;
            for (int b2 = 0; b2 < NTGT; ++b2) {
                int d0 = dp[b2], d1 = dp[b2 + 1];
                for (int k = d0; k < d1; ++k) {
                    int4 r = *(const int4*)(run + (size_t)k * 4);
                    unsigned w0 = (unsigned)r.x;
                    if ((w0 >> t) & 1u) {
                        int post = b2 * NN_PER_BLK + (int)(w0 >> 20);
                        atomicAdd(&inpi[post * NSYN + 0], (int)((unsigned)r.y & 0xFFFFu));
                        atomicAdd(&inpi[post * NSYN + 1], (int)((unsigned)r.y >> 16));
                        atomicAdd(&inpi[post * NSYN + 2], (int)((unsigned)r.z & 0xFFFFu));
                        atomicAdd(&inpi[post * NSYN + 3], (int)((unsigned)r.z >> 16));
                        atomicAdd(&inpi[post * NSYN + 4], r.w);
                    }
                }
            }
        }
        __syncthreads();
        if (t > 0) {
            for (int e = tid; e < E_REC; e += 1024) {
                int2 pcol = ((const int2*)rec_idx)[e];
                int post = pcol.x, col = pcol.y;
                int d1 = col / N_NEURONS;
                int pre = col - d1 * N_NEURONS;
                int st = t - 1 - d1;
                if (st < 0) continue;
                if (zbuf[(st % MAX_DELAY) * N_NEURONS + pre] != 0.0f) {
                    float w = rec_w[e];
                    atomicAdd(&inpi[post * NSYN + 0], __float2int_rn(w * rec_fac[5 * e + 0] * SCALE_F));
                    atomicAdd(&inpi[post * NSYN + 1], __float2int_rn(w * rec_fac[5 * e + 1] * SCALE_F));
                    atomicAdd(&inpi[post * NSYN + 2], __float2int_rn(w * rec_fac[5 * e + 2] * SCALE_F));
                    atomicAdd(&inpi[post * NSYN + 3], __float2int_rn(w * rec_fac[5 * e + 3] * SCALE_F));
                    atomicAdd(&inpi[post * NSYN + 4], __float2int_rn(w * rec_fac[5 * e + 4] * SCALE_F));
                }
            }
        }
        __syncthreads();
        for (int n = tid; n < N_NEURONS; n += 1024) {
            float pz = (t == 0) ? 0.f : zbuf[((t - 1) % MAX_DELAY) * N_NEURONS + n];
            float prx[NSYN], pcx[NSYN];
            float ic = 0.f;
#pragma unroll
            for (int s = 0; s < NSYN; ++s) {
                prx[s] = pra[n * NSYN + s];
                pcx[s] = pca[n * NSYN + s];
                ic += pcx[s];
            }
            float a0 = asc[2 * n], a1 = asc[2 * n + 1];
            float c1 = ic + a0 + a1 + gg[n];
            float dv = decay[n] * vv[n] + cf[n] * c1;
            float nv = (pz > 0.5f) ? vres[n] : dv;
            float tr = tref[n];
            float nr = rr[n] + pz * tr - DT;
            nr = fminf(fmaxf(nr, 0.0f), tr);
            asc[2 * n]     = expf(-DT * kk[2 * n])     * a0 + pz * aamps[2 * n];
            asc[2 * n + 1] = expf(-DT * kk[2 * n + 1]) * a1 + pz * aamps[2 * n + 1];
#pragma unroll
            for (int s = 0; s < NSYN; ++s) {
                float is = (float)((double)inpi[n * NSYN + s] * INV_SCALE);
                float sd = sdec[s];
                float np = pcx[s] * sd + DT * sd * prx[s];
                pra[n * NSYN + s] = prx[s] * sd + is * psci[s];
                pca[n * NSYN + s] = np;
            }
            vv[n] = nv; rr[n] = nr;
            float vsc = (nv - vth[n]) / norm[n];
            float z = (vsc > 0.0f) ? 1.0f : 0.0f;
            float nz = (nr > 0.0f) ? 0.0f : z;
            zbuf[(t % MAX_DELAY) * N_NEURONS + n] = nz;
            out[(size_t)t * N_NEURONS + n] = nz;
        }
        __syncthreads();
    }
}

extern "C" void kernel_launch(void* const* d_in, const int* in_sizes, int n_in,
                              void* d_out, int out_size, void* d_ws, size_t ws_size,
                              hipStream_t stream) {
    const float* lgn_spikes  = (const float*)d_in[0];
    const float* bkg_spikes  = (const float*)d_in[1];
    const int*   rec_indices = (const int*)  d_in[2];
    const float* rec_w       = (const float*)d_in[3];
    const float* rec_factors = (const float*)d_in[4];
    const int*   lgn_indices = (const int*)  d_in[5];
    const float* lgn_w       = (const float*)d_in[6];
    const float* lgn_factors = (const float*)d_in[7];
    const int*   bkg_indices = (const int*)  d_in[8];
    const float* bkg_w       = (const float*)d_in[9];
    const float* bkg_factors = (const float*)d_in[10];
    const float* decay       = (const float*)d_in[11];
    const float* current_factor = (const float*)d_in[12];
    const float* v_reset     = (const float*)d_in[13];
    const float* t_ref       = (const float*)d_in[14];
    const float* k           = (const float*)d_in[15];
    const float* asc_amps    = (const float*)d_in[16];
    const float* v_th        = (const float*)d_in[17];
    const float* normalizer  = (const float*)d_in[18];
    const float* gathered_g  = (const float*)d_in[19];
    const float* syn_decay   = (const float*)d_in[20];
    const float* psc_initial = (const float*)d_in[21];

    float* ws = (float*)d_ws;
    int*      flag = (int*)(ws + OFF_FLAG);
    unsigned* bits = (unsigned*)(ws + OFF_BITS);
    int*      dir  = (int*)(ws + OFF_DIR);
    int*      runs = (int*)(ws + OFF_RUNS);
    float*    zbuf = ws + OFF_ZBUF;
    float*    vv   = ws + OFF_V;
    float*    rr   = ws + OFF_R;
    float*    asc  = ws + OFF_ASC;
    float*    pra  = ws + OFF_PR;
    float*    pca  = ws + OFF_PC;
    int*      inpi = (int*)(ws + OFF_INPI);
    float*    out  = (float*)d_out;

    prep<<<(32 + N_SRC + 255) / 256, 256, 0, stream>>>(lgn_spikes, bkg_spikes, bits, flag);
    sort_pack<<<NCHUNK, 1024, 0, stream>>>(
        lgn_indices, lgn_w, lgn_factors, bkg_indices, bkg_w, bkg_factors,
        bits, dir, runs);
    fused_scan<<<NTGT, 256, 0, stream>>>(
        dir, runs,
        decay, current_factor, v_reset, t_ref, k, asc_amps,
        v_th, normalizer, gathered_g, syn_decay, psc_initial,
        out, flag);
    fallback_redo<<<1, 1024, 0, stream>>>(
        dir, runs, rec_indices, rec_w, rec_factors,
        decay, current_factor, v_reset, t_ref, k, asc_amps,
        v_th, normalizer, gathered_g, syn_decay, psc_initial,
        zbuf, vv, rr, asc, pra, pca, inpi, out, flag);
}

// Round 17
// 40.054 us; speedup vs baseline: 1.0770x; 1.0770x over previous
//
#include <hip/hip_runtime.h>

#define N_NEURONS 100000
#define MAX_DELAY 5
#define NSYN 5
#define T_STEPS 20
#define N_LGN 17400
#define N_BKG 100
#define N_SRC (N_LGN + N_BKG)        // 17500
#define E_REC 2000000
#define E_LGN 600000
#define E_BKG 200000
#define E_EXT (E_LGN + E_BKG)        // 800000
#define DT 1.0f
#define NN_PER_BLK 64
#define NTGT 1563                    // consumer blocks = ceil(N/64)
#define NHP 782                      // packed histogram entries (2 targets/int)
#define DIRW (NTGT + 1)              // 1564
#define NCHUNK 256                   // producer chunks (r15 optimum)
#define CHUNK 3125                   // 256*3125 = 800,000 == E_EXT exactly
#define RUNW (CHUNK * 4)             // ints per chunk run region (16B records)
#define ASTR 21                      // per-neuron acc stride (20 + 1 pad)
#define SCALE_F 262144.0f            // 2^18 fixed-point; q fits u16 (max ~29K)
#define INV_SCALE (1.0 / 262144.0)

// ---------------- ws layout (4-byte units) ----------------
#define OFF_FLAG   0u                // int[32]: [0]=any-spike flag
#define OFF_BITS   32u               // uint[N_SRC]
#define OFF_DIR    17536u            // int[NCHUNK][DIRW] = 400,384
#define OFF_RUNS   417920u           // int[NCHUNK][CHUNK][4] = 3,200,000
#define OFF_ZBUF   3617920u          // float[5N]  (fallback only)
#define OFF_V      4117920u
#define OFF_R      4217920u
#define OFF_ASC    4317920u          // float[2N]
#define OFF_PR     4517920u          // float[5N]
#define OFF_PC     5017920u          // float[5N]
#define OFF_INPI   5517920u          // int[5N]
// ends 6,017,920 units = 24.1 MB

// Zero flag + build 20-bit spike masks.
__global__ void prep(const float* __restrict__ lgn, const float* __restrict__ bkg,
                     unsigned* __restrict__ bits, int* __restrict__ zp) {
    int tid = blockIdx.x * blockDim.x + threadIdx.x;
    if (tid < 32) zp[tid] = 0;
    int i = tid - 32;
    if (i < 0 || i >= N_SRC) return;
    unsigned b = 0;
    if (i < N_LGN) {
#pragma unroll
        for (int t = 0; t < T_STEPS; ++t)
            if (lgn[t * N_LGN + i] != 0.0f) b |= (1u << t);
    } else {
        int j = i - N_LGN;
#pragma unroll
        for (int t = 0; t < T_STEPS; ++t)
            if (bkg[t * N_BKG + j] != 0.0f) b |= (1u << t);
    }
    bits[i] = b;
}

// Counting-sort pack with LDS record staging + u16-PACKED histogram:
// two adjacent targets share one int (counts < 2^16, no cross-carry), so
// the per-block fixed routing cost (zero + scan) is halved vs r15.
// Records are built at their cursor slot in LDS, then streamed to global
// with fully coalesced int4 stores (full 64B lines).
// Zero global atomics; slot order varies across replays (LDS cursor) but
// consumer integer accumulation is order-invariant -> deterministic output.
__global__ void __launch_bounds__(1024) sort_pack(
    const int* __restrict__ lgn_idx, const float* __restrict__ lgn_w,
    const float* __restrict__ lgn_fac,
    const int* __restrict__ bkg_idx, const float* __restrict__ bkg_w,
    const float* __restrict__ bkg_fac,
    const unsigned* __restrict__ bits,
    int* __restrict__ dir, int* __restrict__ runs)
{
    __shared__ unsigned hp[NHP];           // packed: lo=target 2i, hi=target 2i+1
    __shared__ int cur[NTGT];
    __shared__ int wsum[16];
    __shared__ int totS;
    __shared__ int4 stage[CHUNK];          // 50 KB staging
    int tid = threadIdx.x, c = blockIdx.x;
    int e0 = c * CHUNK;

    if (tid < NHP) hp[tid] = 0u;

    // Phase A: load (mask, post) for up to 4 edges into registers.
    unsigned mm[4];
    int pp[4];
#pragma unroll
    for (int k = 0; k < 4; ++k) {
        mm[k] = 0; pp[k] = 0;
        int e = e0 + tid + k * 1024;
        if (e < e0 + CHUNK) {
            int post, srow;
            if (e < E_LGN) { int2 p = ((const int2*)lgn_idx)[e]; post = p.x; srow = p.y; }
            else           { int2 p = ((const int2*)bkg_idx)[e - E_LGN]; post = p.x; srow = N_LGN + p.y; }
            unsigned m = bits[srow];
            if (m) { mm[k] = m; pp[k] = post; }
        }
    }
    __syncthreads();

#pragma unroll
    for (int k = 0; k < 4; ++k)
        if (mm[k]) atomicAdd(&hp[pp[k] >> 7], 1u << (((pp[k] >> 6) & 1) * 16));
    __syncthreads();

    // Exclusive scan over 782 packed entries (1/thread, wave-shuffle).
    // Packed halves scan independently: each half's total < 2^16.
    unsigned v = (tid < NHP) ? hp[tid] : 0u;
    int lane = tid & 63, wid = tid >> 6;
    unsigned inc = v;
#pragma unroll
    for (int off = 1; off < 64; off <<= 1) {
        unsigned u = __shfl_up(inc, off);
        if (lane >= off) inc += u;
    }
    if (lane == 63) wsum[wid] = (int)inc;
    __syncthreads();
    if (tid < 16) {
        int x = wsum[tid];
        int i2 = x;
#pragma unroll
        for (int off = 1; off < 16; off <<= 1) {
            int u = __shfl_up(i2, off);
            if (tid >= off) i2 += u;
        }
        wsum[tid] = i2 - x;   // exclusive wave offset (packed)
    }
    __syncthreads();
    if (tid < NHP) {
        unsigned ep = (unsigned)wsum[wid] + (inc - v);          // packed exclusive prefix
        int exclEven = (int)(ep & 0xFFFFu) + (int)(ep >> 16);   // sum of all targets < 2*tid
        int cntEven  = (int)(v & 0xFFFFu);
        int t0 = 2 * tid, t1 = 2 * tid + 1;
        cur[t0] = exclEven;
        dir[(size_t)c * DIRW + t0] = exclEven;
        int exclOdd = exclEven + cntEven;
        if (t1 < NTGT) {
            cur[t1] = exclOdd;
            dir[(size_t)c * DIRW + t1] = exclOdd;
        } else {                                                // t1 == NTGT (tid==781)
            totS = exclOdd;                                     // total firing count
            dir[(size_t)c * DIRW + NTGT] = exclOdd;
        }
    }
    __syncthreads();

    // Phase B: load w/fac (independent, latency-hidden), quantize, stage in LDS.
#pragma unroll
    for (int k = 0; k < 4; ++k) {
        if (mm[k]) {
            int e = e0 + tid + k * 1024;
            float w; const float* f;
            if (e < E_LGN) { w = lgn_w[e]; f = lgn_fac + 5 * (size_t)e; }
            else { int b = e - E_LGN; w = bkg_w[b]; f = bkg_fac + 5 * (size_t)b; }
            float wsc = w * SCALE_F;
            int q0 = __float2int_rn(wsc * f[0]);
            int q1 = __float2int_rn(wsc * f[1]);
            int q2 = __float2int_rn(wsc * f[2]);
            int q3 = __float2int_rn(wsc * f[3]);
            int q4 = __float2int_rn(wsc * f[4]);
            int slot = atomicAdd(&cur[pp[k] >> 6], 1);  // LDS atomic
            stage[slot] = make_int4((int)(mm[k] | ((unsigned)(pp[k] & 63) << 20)),
                                    q0 | (q1 << 16), q2 | (q3 << 16), q4);
        }
    }
    __syncthreads();

    // Phase C: stream staging to global, fully coalesced (full 64B lines).
    int tot = totS;
    int* run = runs + (size_t)c * RUNW;
    for (int k2 = tid; k2 < tot; k2 += 1024)
        *(int4*)(run + (size_t)k2 * 4) = stage[k2];
}

// Consumer (XCD-swizzled blockIdx): thread t streams chunk t's group for
// this block (ONE int4 load per record), 3 LDS atomics per spike-bit
// (u64-packed pairs; non-negative fields, no carry -> exact, order-invariant);
// then 64 threads run the 20-step GLIF scan.
__global__ void __launch_bounds__(256) fused_scan(
    const int* __restrict__ dir, const int* __restrict__ runs,
    const float* __restrict__ decay, const float* __restrict__ cf,
    const float* __restrict__ vres, const float* __restrict__ tref,
    const float* __restrict__ kk, const float* __restrict__ aamps,
    const float* __restrict__ vth, const float* __restrict__ norm,
    const float* __restrict__ gg, const float* __restrict__ sdec,
    const float* __restrict__ psci,
    float* __restrict__ out, int* __restrict__ flag)
{
    __shared__ unsigned long long a01[NN_PER_BLK * ASTR];   // q0 | q1<<32
    __shared__ unsigned long long a23[NN_PER_BLK * ASTR];   // q2 | q3<<32
    __shared__ unsigned a4[NN_PER_BLK * ASTR];
    int tid = threadIdx.x;
    // Bijective XCD swizzle (NTGT = 1563 = 8*195+3).
    int bid = blockIdx.x;
    int xcd = bid & 7, idx = bid >> 3;
    int b = (xcd < 3) ? (xcd * 196 + idx) : (588 + (xcd - 3) * 195 + idx);
    int n0 = b * NN_PER_BLK;

    for (int i = tid; i < NN_PER_BLK * ASTR; i += 256) { a01[i] = 0ull; a23[i] = 0ull; a4[i] = 0u; }
    __syncthreads();

    {
        int cc = tid;   // NCHUNK == 256 == blockDim
        const int* dp = dir + (size_t)cc * DIRW + b;
        int d0 = dp[0], d1 = dp[1];
        const int* run = runs + (size_t)cc * RUNW;
        for (int k = d0; k < d1; ++k) {
            int4 r = *(const int4*)(run + (size_t)k * 4);
            unsigned w0 = (unsigned)r.x;
            unsigned m = w0 & 0xFFFFFu;
            int pl = (int)(w0 >> 20);
            unsigned long long q01 = (unsigned long long)((unsigned)r.y & 0xFFFFu)
                                   | ((unsigned long long)((unsigned)r.y >> 16) << 32);
            unsigned long long q23 = (unsigned long long)((unsigned)r.z & 0xFFFFu)
                                   | ((unsigned long long)((unsigned)r.z >> 16) << 32);
            unsigned q4v = (unsigned)r.w;
            int basei = pl * ASTR;
            while (m) {
                int t = __ffs(m) - 1;
                m &= m - 1;
                atomicAdd(&a01[basei + t], q01);
                atomicAdd(&a23[basei + t], q23);
                atomicAdd(&a4[basei + t], q4v);
            }
        }
    }
    __syncthreads();

    if (tid >= NN_PER_BLK) return;
    int n = n0 + tid;
    if (n >= N_NEURONS) return;

    float dec = decay[n], cfa = cf[n], vr = vres[n], tr = tref[n];
    float ek0 = expf(-DT * kk[2 * n]), ek1 = expf(-DT * kk[2 * n + 1]);
    float aa0 = aamps[2 * n], aa1 = aamps[2 * n + 1];
    float vt = vth[n], nm = norm[n], g = gg[n];
    float sd0 = sdec[0], sd1 = sdec[1], sd2 = sdec[2], sd3 = sdec[3], sd4 = sdec[4];
    float pi0 = psci[0], pi1 = psci[1], pi2 = psci[2], pi3 = psci[3], pi4 = psci[4];

    float pr0 = 0.f, pr1 = 0.f, pr2 = 0.f, pr3 = 0.f, pr4 = 0.f;
    float pc0 = 0.f, pc1 = 0.f, pc2 = 0.f, pc3 = 0.f, pc4 = 0.f;
    float v = 0.f, r = 0.f, a0 = 0.f, a1 = 0.f, pz = 0.f;
    bool anyf = false;
    int basei = tid * ASTR;

#pragma unroll
    for (int t = 0; t < T_STEPS; ++t) {
        float ic = pc0 + pc1 + pc2 + pc3 + pc4;      // input_current uses OLD psc
        float c1 = ic + a0 + a1 + g;
        float dv = dec * v + cfa * c1;
        float nv = (pz > 0.5f) ? vr : dv;
        float nr = r + pz * tr - DT;
        nr = fminf(fmaxf(nr, 0.0f), tr);
        a0 = ek0 * a0 + pz * aa0;
        a1 = ek1 * a1 + pz * aa1;

        unsigned long long v01 = a01[basei + t];
        unsigned long long v23 = a23[basei + t];
        float i0 = (float)((double)(unsigned)(v01 & 0xFFFFFFFFull) * INV_SCALE);
        float i1 = (float)((double)(unsigned)(v01 >> 32) * INV_SCALE);
        float i2 = (float)((double)(unsigned)(v23 & 0xFFFFFFFFull) * INV_SCALE);
        float i3 = (float)((double)(unsigned)(v23 >> 32) * INV_SCALE);
        float i4 = (float)((double)a4[basei + t] * INV_SCALE);

        float np0 = pc0 * sd0 + DT * sd0 * pr0;      // new psc from OLD psc_rise
        float np1 = pc1 * sd1 + DT * sd1 * pr1;
        float np2 = pc2 * sd2 + DT * sd2 * pr2;
        float np3 = pc3 * sd3 + DT * sd3 * pr3;
        float np4 = pc4 * sd4 + DT * sd4 * pr4;
        pr0 = pr0 * sd0 + i0 * pi0;  pc0 = np0;
        pr1 = pr1 * sd1 + i1 * pi1;  pc1 = np1;
        pr2 = pr2 * sd2 + i2 * pi2;  pc2 = np2;
        pr3 = pr3 * sd3 + i3 * pi3;  pc3 = np3;
        pr4 = pr4 * sd4 + i4 * pi4;  pc4 = np4;

        v = nv; r = nr;
        float vsc = (nv - vt) / nm;
        float z = (vsc > 0.0f) ? 1.0f : 0.0f;
        float nz = (nr > 0.0f) ? 0.0f : z;
        out[(size_t)t * N_NEURONS + n] = nz;
        pz = nz;
        anyf = anyf || (nz != 0.0f);
    }
    if (anyf) atomicAdd(flag, 1);
}

// Exact coupled redo inside ONE workgroup; early-exits if no spike detected.
__global__ void __launch_bounds__(1024) fallback_redo(
    const int* __restrict__ dir, const int* __restrict__ runs,
    const int* __restrict__ rec_idx, const float* __restrict__ rec_w,
    const float* __restrict__ rec_fac,
    const float* __restrict__ decay, const float* __restrict__ cf,
    const float* __restrict__ vres, const float* __restrict__ tref,
    const float* __restrict__ kk, const float* __restrict__ aamps,
    const float* __restrict__ vth, const float* __restrict__ norm,
    const float* __restrict__ gg, const float* __restrict__ sdec,
    const float* __restrict__ psci,
    float* __restrict__ zbuf, float* __restrict__ vv, float* __restrict__ rr,
    float* __restrict__ asc, float* __restrict__ pra, float* __restrict__ pca,
    int* __restrict__ inpi, float* __restrict__ out, const int* __restrict__ flag)
{
    if (flag[0] == 0) return;
    int tid = threadIdx.x;
    for (int i = tid; i < N_NEURONS; i += 1024) { vv[i] = 0.f; rr[i] = 0.f; }
    for (int i = tid; i < 2 * N_NEURONS; i += 1024) asc[i] = 0.f;
    for (int i = tid; i < NSYN * N_NEURONS; i += 1024) { pra[i] = 0.f; pca[i] = 0.f; }
    for (int i = tid; i < MAX_DELAY * N_NEURONS; i += 1024) zbuf[i] = 0.f;
    __syncthreads();

    for (int t = 0; t < T_STEPS; ++t) {
        for (int i = tid; i < NSYN * N_NEURONS; i += 1024) inpi[i] = 0;
        __syncthreads();
        if (tid < NCHUNK) {
            const int* dp  = dir + (size_t)tid * DIRW;
            const int* run = runs + (size_t)tid * RUNW;
            for (int b2 = 0; b2 < NTGT; ++b2) {
                int d0 = dp[b2], d1 = dp[b2 + 1];
                for (int k = d0; k < d1; ++k) {
                    int4 r = *(const int4*)(run + (size_t)k * 4);
                    unsigned w0 = (unsigned)r.x;
                    if ((w0 >> t) & 1u) {
                        int post = b2 * NN_PER_BLK + (int)(w0 >> 20);
                        atomicAdd(&inpi[post * NSYN + 0], (int)((unsigned)r.y & 0xFFFFu));
                        atomicAdd(&inpi[post * NSYN + 1], (int)((unsigned)r.y >> 16));
                        atomicAdd(&inpi[post * NSYN + 2], (int)((unsigned)r.z & 0xFFFFu));
                        atomicAdd(&inpi[post * NSYN + 3], (int)((unsigned)r.z >> 16));
                        atomicAdd(&inpi[post * NSYN + 4], r.w);
                    }
                }
            }
        }
        __syncthreads();
        if (t > 0) {
            for (int e = tid; e < E_REC; e += 1024) {
                int2 pcol = ((const int2*)rec_idx)[e];
                int post = pcol.x, col = pcol.y;
                int d1 = col / N_NEURONS;
                int pre = col - d1 * N_NEURONS;
                int st = t - 1 - d1;
                if (st < 0) continue;
                if (zbuf[(st % MAX_DELAY) * N_NEURONS + pre] != 0.0f) {
                    float w = rec_w[e];
                    atomicAdd(&inpi[post * NSYN + 0], __float2int_rn(w * rec_fac[5 * e + 0] * SCALE_F));
                    atomicAdd(&inpi[post * NSYN + 1], __float2int_rn(w * rec_fac[5 * e + 1] * SCALE_F));
                    atomicAdd(&inpi[post * NSYN + 2], __float2int_rn(w * rec_fac[5 * e + 2] * SCALE_F));
                    atomicAdd(&inpi[post * NSYN + 3], __float2int_rn(w * rec_fac[5 * e + 3] * SCALE_F));
                    atomicAdd(&inpi[post * NSYN + 4], __float2int_rn(w * rec_fac[5 * e + 4] * SCALE_F));
                }
            }
        }
        __syncthreads();
        for (int n = tid; n < N_NEURONS; n += 1024) {
            float pz = (t == 0) ? 0.f : zbuf[((t - 1) % MAX_DELAY) * N_NEURONS + n];
            float prx[NSYN], pcx[NSYN];
            float ic = 0.f;
#pragma unroll
            for (int s = 0; s < NSYN; ++s) {
                prx[s] = pra[n * NSYN + s];
                pcx[s] = pca[n * NSYN + s];
                ic += pcx[s];
            }
            float a0 = asc[2 * n], a1 = asc[2 * n + 1];
            float c1 = ic + a0 + a1 + gg[n];
            float dv = decay[n] * vv[n] + cf[n] * c1;
            float nv = (pz > 0.5f) ? vres[n] : dv;
            float tr = tref[n];
            float nr = rr[n] + pz * tr - DT;
            nr = fminf(fmaxf(nr, 0.0f), tr);
            asc[2 * n]     = expf(-DT * kk[2 * n])     * a0 + pz * aamps[2 * n];
            asc[2 * n + 1] = expf(-DT * kk[2 * n + 1]) * a1 + pz * aamps[2 * n + 1];
#pragma unroll
            for (int s = 0; s < NSYN; ++s) {
                float is = (float)((double)inpi[n * NSYN + s] * INV_SCALE);
                float sd = sdec[s];
                float np = pcx[s] * sd + DT * sd * prx[s];
                pra[n * NSYN + s] = prx[s] * sd + is * psci[s];
                pca[n * NSYN + s] = np;
            }
            vv[n] = nv; rr[n] = nr;
            float vsc = (nv - vth[n]) / norm[n];
            float z = (vsc > 0.0f) ? 1.0f : 0.0f;
            float nz = (nr > 0.0f) ? 0.0f : z;
            zbuf[(t % MAX_DELAY) * N_NEURONS + n] = nz;
            out[(size_t)t * N_NEURONS + n] = nz;
        }
        __syncthreads();
    }
}

extern "C" void kernel_launch(void* const* d_in, const int* in_sizes, int n_in,
                              void* d_out, int out_size, void* d_ws, size_t ws_size,
                              hipStream_t stream) {
    const float* lgn_spikes  = (const float*)d_in[0];
    const float* bkg_spikes  = (const float*)d_in[1];
    const int*   rec_indices = (const int*)  d_in[2];
    const float* rec_w       = (const float*)d_in[3];
    const float* rec_factors = (const float*)d_in[4];
    const int*   lgn_indices = (const int*)  d_in[5];
    const float* lgn_w       = (const float*)d_in[6];
    const float* lgn_factors = (const float*)d_in[7];
    const int*   bkg_indices = (const int*)  d_in[8];
    const float* bkg_w       = (const float*)d_in[9];
    const float* bkg_factors = (const float*)d_in[10];
    const float* decay       = (const float*)d_in[11];
    const float* current_factor = (const float*)d_in[12];
    const float* v_reset     = (const float*)d_in[13];
    const float* t_ref       = (const float*)d_in[14];
    const float* k           = (const float*)d_in[15];
    const float* asc_amps    = (const float*)d_in[16];
    const float* v_th        = (const float*)d_in[17];
    const float* normalizer  = (const float*)d_in[18];
    const float* gathered_g  = (const float*)d_in[19];
    const float* syn_decay   = (const float*)d_in[20];
    const float* psc_initial = (const float*)d_in[21];

    float* ws = (float*)d_ws;
    int*      flag = (int*)(ws + OFF_FLAG);
    unsigned* bits = (unsigned*)(ws + OFF_BITS);
    int*      dir  = (int*)(ws + OFF_DIR);
    int*      runs = (int*)(ws + OFF_RUNS);
    float*    zbuf = ws + OFF_ZBUF;
    float*    vv   = ws + OFF_V;
    float*    rr   = ws + OFF_R;
    float*    asc  = ws + OFF_ASC;
    float*    pra  = ws + OFF_PR;
    float*    pca  = ws + OFF_PC;
    int*      inpi = (int*)(ws + OFF_INPI);
    float*    out  = (float*)d_out;

    prep<<<(32 + N_SRC + 255) / 256, 256, 0, stream>>>(lgn_spikes, bkg_spikes, bits, flag);
    sort_pack<<<NCHUNK, 1024, 0, stream>>>(
        lgn_indices, lgn_w, lgn_factors, bkg_indices, bkg_w, bkg_factors,
        bits, dir, runs);
    fused_scan<<<NTGT, 256, 0, stream>>>(
        dir, runs,
        decay, current_factor, v_reset, t_ref, k, asc_amps,
        v_th, normalizer, gathered_g, syn_decay, psc_initial,
        out, flag);
    fallback_redo<<<1, 1024, 0, stream>>>(
        dir, runs, rec_indices, rec_w, rec_factors,
        decay, current_factor, v_reset, t_ref, k, asc_amps,
        v_th, normalizer, gathered_g, syn_decay, psc_initial,
        zbuf, vv, rr, asc, pra, pca, inpi, out, flag);
}